// Round 4
// baseline (660.396 us; speedup 1.0000x reference)
//
#include <hip/hip_runtime.h>

// Problem constants
#define B_TOK 32768
#define D_IN  256
#define H1D   512
#define H2D   256
#define NE    16
#define NO    64
#define TK    128            // tokens per block

typedef _Float16 half8 __attribute__((ext_vector_type(8)));
typedef _Float16 half4 __attribute__((ext_vector_type(4)));
typedef float   float4_t __attribute__((ext_vector_type(4)));

// ---------------------------------------------------------------------------
// Fused prep kernel (grid 2066 x 256):
//  blocks 0..1023    : pack W1 [E][D][H1] fp32 -> fragment-linear fp16
//  blocks 1024..2047 : pack W2 [E][H1][H2] fp32 -> fragment-linear fp16
//  blocks 2048..2064 : w3h[e][h2] = W3[e][h2][:].head_w ; c3[e] = b3[e][:].head_w
//  block  2065       : pack gate_w [D][E] -> 8 B-fragments
// ---------------------------------------------------------------------------
__global__ void prep_kernel(const float* __restrict__ W1, const float* __restrict__ W2,
                            const float* __restrict__ W3, const float* __restrict__ b3,
                            const float* __restrict__ hw, const float* __restrict__ gw,
                            _Float16* __restrict__ w1p, _Float16* __restrict__ w2p,
                            float* __restrict__ w3h, float* __restrict__ c3,
                            _Float16* __restrict__ gwp) {
  int blk = blockIdx.x;
  int tid = threadIdx.x;
  if (blk < 1024) {
    int t = blk * 256 + tid;                     // 262144 threads
    int lane = t & 63;
    int kt   = (t >> 6) & 7;
    int ntg  = (t >> 9) & 31;
    int e    = t >> 14;
    int n  = ntg * 16 + (lane & 15);
    int kb = kt * 32 + (lane >> 4) * 8;
    half8 v;
    #pragma unroll
    for (int j = 0; j < 8; ++j)
      v[j] = (_Float16)W1[((size_t)(e * D_IN + kb + j)) * H1D + n];
    *(half8*)(w1p + (size_t)t * 8) = v;
  } else if (blk < 2048) {
    int t = (blk - 1024) * 256 + tid;            // 262144 threads
    int lane = t & 63;
    int ktg  = (t >> 6) & 15;
    int ntg  = (t >> 10) & 15;
    int e    = t >> 14;
    int n  = ntg * 16 + (lane & 15);
    int kb = ktg * 32 + (lane >> 4) * 8;
    half8 v;
    #pragma unroll
    for (int j = 0; j < 8; ++j)
      v[j] = (_Float16)W2[((size_t)(e * H1D + kb + j)) * H2D + n];
    *(half8*)(w2p + (size_t)t * 8) = v;
  } else if (blk < 2065) {
    int t = (blk - 2048) * 256 + tid;
    if (t < NE * H2D) {
      int e = t >> 8, h = t & 255;
      float s = 0.f;
      #pragma unroll
      for (int o = 0; o < NO; ++o) s = fmaf(W3[((size_t)(e * H2D + h)) * NO + o], hw[o], s);
      w3h[t] = s;
    } else if (t < NE * H2D + NE) {
      int e = t - NE * H2D;
      float s = 0.f;
      #pragma unroll
      for (int o = 0; o < NO; ++o) s = fmaf(b3[e * NO + o], hw[o], s);
      c3[e] = s;
    }
  } else {
    for (int t = tid; t < 512; t += 256) {
      int lane = t & 63;
      int kt   = t >> 6;
      int e  = lane & 15;
      int kb = kt * 32 + (lane >> 4) * 8;
      half8 v;
      #pragma unroll
      for (int j = 0; j < 8; ++j)
        v[j] = (_Float16)gw[(kb + j) * NE + e];
      *(half8*)(gwp + (size_t)t * 8) = v;
    }
  }
}

// ---------------------------------------------------------------------------
// Fused main kernel. 256 blocks x 1024 threads (16 waves, 4/SIMD), 128 tok/blk.
// Wave w: tp = w>>2 owns token-tiles {2tp, 2tp+1} (x frags in registers);
//         ng = w&3 owns h1col-tiles ng*8..+7 (L1) and h2col-tiles ng*4..+3 (L2).
// Per expert: L1 (A=W1^T frags from global, B=x regs) -> h1 [128][512] LDS
//   -> barrier -> L2 (A=h1 LDS, B=W2 frags global) -> reg epilogue with gate
//   folded into per-lane accumulator -> barrier (WAR on h1).
// Single 16-lane shuffle reduction at the very end.
// ---------------------------------------------------------------------------
#define H1STR 520   // halves: 512 + 8 pad (row stride 260 dw == 4 mod 32)

__global__ __launch_bounds__(1024, 4) void moe_main(
    const float* __restrict__ x,
    const float* __restrict__ b1,
    const float* __restrict__ b2,
    const _Float16* __restrict__ w1p,
    const _Float16* __restrict__ w2p,
    const _Float16* __restrict__ gwp,
    const float* __restrict__ gb,
    const float* __restrict__ w3h,
    const float* __restrict__ c3,
    const float* __restrict__ head_b,
    float* __restrict__ out) {
  __shared__ _Float16 h1_lds[TK * H1STR];          // 133,120 B
  __shared__ float g_lds[TK * 17];                 // 8,704 B  [token][e] padded
  __shared__ float fin[4 * TK];                    // 2,048 B

  const int tid  = threadIdx.x;
  const int w    = tid >> 6;                       // 0..15
  const int lane = tid & 63;
  const int q    = lane >> 4;
  const int l16  = lane & 15;
  const int tp   = w >> 2;                         // token-tile pair 0..3
  const int ng   = w & 3;                          // n-group 0..3
  const int m0   = blockIdx.x * TK;

  // ---- one-time: this wave's 2 token-tiles of x into register fragments ---
  half8 xf[2][8];
  #pragma unroll
  for (int mi = 0; mi < 2; ++mi) {
    const float* xr = x + (size_t)(m0 + (2 * tp + mi) * 16 + l16) * D_IN + q * 8;
    #pragma unroll
    for (int kt = 0; kt < 8; ++kt) {
      float4_t v0 = *(const float4_t*)(xr + kt * 32);
      float4_t v1 = *(const float4_t*)(xr + kt * 32 + 4);
      half8 h;
      h[0] = (_Float16)v0[0]; h[1] = (_Float16)v0[1];
      h[2] = (_Float16)v0[2]; h[3] = (_Float16)v0[3];
      h[4] = (_Float16)v1[0]; h[5] = (_Float16)v1[1];
      h[6] = (_Float16)v1[2]; h[7] = (_Float16)v1[3];
      xf[mi][kt] = h;
    }
  }

  // ---- one-time: gates via MFMA + shuffle softmax (waves with ng==0) ------
  if (ng == 0) {
    float gbv = gb[l16];
    #pragma unroll
    for (int mi = 0; mi < 2; ++mi) {
      float4_t lg = (float4_t){0.f, 0.f, 0.f, 0.f};
      #pragma unroll
      for (int kt = 0; kt < 8; ++kt) {
        half8 bfr = *(const half8*)(gwp + (size_t)kt * 512 + lane * 8);
        lg = __builtin_amdgcn_mfma_f32_16x16x32_f16(xf[mi][kt], bfr, lg, 0, 0, 0);
      }
      #pragma unroll
      for (int r = 0; r < 4; ++r) {
        float v = lg[r] + gbv;                     // logit[token][e=l16]
        float m = v;
        m = fmaxf(m, __shfl_xor(m, 1));
        m = fmaxf(m, __shfl_xor(m, 2));
        m = fmaxf(m, __shfl_xor(m, 4));
        m = fmaxf(m, __shfl_xor(m, 8));
        float p = __expf(v - m);
        float s = p;
        s += __shfl_xor(s, 1);
        s += __shfl_xor(s, 2);
        s += __shfl_xor(s, 4);
        s += __shfl_xor(s, 8);
        int tok = (2 * tp + mi) * 16 + q * 4 + r;
        g_lds[tok * 17 + l16] = p / s;
      }
    }
  }

  float yacc[2][4];
  #pragma unroll
  for (int mi = 0; mi < 2; ++mi)
    #pragma unroll
    for (int r = 0; r < 4; ++r) yacc[mi][r] = 0.f;

  for (int e = 0; e < NE; ++e) {
    // ================= L1: h1^T = W1^T x, two n-halves of 4 tiles ==========
    #pragma unroll
    for (int nh = 0; nh < 2; ++nh) {
      float4_t a1[2][4];
      #pragma unroll
      for (int mi = 0; mi < 2; ++mi)
        #pragma unroll
        for (int nt = 0; nt < 4; ++nt)
          a1[mi][nt] = (float4_t){0.f, 0.f, 0.f, 0.f};

      const _Float16* w1e =
          w1p + ((size_t)((e * 32 + ng * 8 + nh * 4) * 8)) * 512 + lane * 8;
      #pragma unroll
      for (int kt = 0; kt < 8; ++kt) {
        half8 wc[4];
        #pragma unroll
        for (int nt = 0; nt < 4; ++nt)
          wc[nt] = *(const half8*)(w1e + (size_t)(nt * 8 + kt) * 512);
        #pragma unroll
        for (int mi = 0; mi < 2; ++mi)
          #pragma unroll
          for (int nt = 0; nt < 4; ++nt)
            a1[mi][nt] = __builtin_amdgcn_mfma_f32_16x16x32_f16(
                wc[nt], xf[mi][kt], a1[mi][nt], 0, 0, 0);
      }

      // bias + relu + b64 stores (lane: 4 consecutive h1cols of one token)
      #pragma unroll
      for (int nt = 0; nt < 4; ++nt) {
        int colbase = (ng * 8 + nh * 4 + nt) * 16 + q * 4;
        float4_t bb = *(const float4_t*)(b1 + e * H1D + colbase);
        #pragma unroll
        for (int mi = 0; mi < 2; ++mi) {
          half4 hv;
          #pragma unroll
          for (int r = 0; r < 4; ++r)
            hv[r] = (_Float16)fmaxf(a1[mi][nt][r] + bb[r], 0.f);
          *(half4*)(h1_lds + ((2 * tp + mi) * 16 + l16) * H1STR + colbase) = hv;
        }
      }
    }

    __syncthreads();   // h1 complete & visible (also makes g_lds visible, e=0)

    // ================= L2: h2 = h1 @ W2, wave owns 4 h2col-tiles ===========
    float4_t h2[2][4];
    #pragma unroll
    for (int mi = 0; mi < 2; ++mi)
      #pragma unroll
      for (int nt = 0; nt < 4; ++nt)
        h2[mi][nt] = (float4_t){0.f, 0.f, 0.f, 0.f};

    const _Float16* w2e =
        w2p + ((size_t)((e * 16 + ng * 4) * 16)) * 512 + lane * 8;
    #pragma unroll
    for (int kt = 0; kt < 16; ++kt) {
      half8 hac[2];
      #pragma unroll
      for (int mi = 0; mi < 2; ++mi)
        hac[mi] = *(const half8*)(h1_lds + ((2 * tp + mi) * 16 + l16) * H1STR + kt * 32 + q * 8);
      half8 w2c[4];
      #pragma unroll
      for (int nt = 0; nt < 4; ++nt)
        w2c[nt] = *(const half8*)(w2e + (size_t)(nt * 16 + kt) * 512);
      #pragma unroll
      for (int mi = 0; mi < 2; ++mi)
        #pragma unroll
        for (int nt = 0; nt < 4; ++nt)
          h2[mi][nt] = __builtin_amdgcn_mfma_f32_16x16x32_f16(
              hac[mi], w2c[nt], h2[mi][nt], 0, 0, 0);
    }

    // ---- register epilogue: relu(h2+b2).w3h, gate folded, accumulate ------
    float b2v[4], w3v[4];
    #pragma unroll
    for (int nt = 0; nt < 4; ++nt) {
      int n = (ng * 4 + nt) * 16 + l16;
      b2v[nt] = b2[e * H2D + n];
      w3v[nt] = w3h[e * H2D + n];
    }
    #pragma unroll
    for (int mi = 0; mi < 2; ++mi) {
      #pragma unroll
      for (int r = 0; r < 4; ++r) {
        float s = 0.f;
        #pragma unroll
        for (int nt = 0; nt < 4; ++nt)
          s += fmaxf(h2[mi][nt][r] + b2v[nt], 0.f) * w3v[nt];
        int tok = (2 * tp + mi) * 16 + q * 4 + r;
        yacc[mi][r] += g_lds[tok * 17 + e] * s;
      }
    }
    __syncthreads();   // WAR: all h1 reads done before next expert's L1 writes
  }

  // ---- single final reduction over the 16 l16-lanes, then cross-wave ------
  #pragma unroll
  for (int mi = 0; mi < 2; ++mi) {
    #pragma unroll
    for (int r = 0; r < 4; ++r) {
      float v = yacc[mi][r];
      v += __shfl_xor(v, 1);
      v += __shfl_xor(v, 2);
      v += __shfl_xor(v, 4);
      v += __shfl_xor(v, 8);
      if (l16 == 0)
        fin[ng * TK + (2 * tp + mi) * 16 + q * 4 + r] = v;
    }
  }
  __syncthreads();
  if (tid < TK) {
    float sum = fin[tid] + fin[TK + tid] + fin[2 * TK + tid] + fin[3 * TK + tid];
    float gc = 0.f;
    #pragma unroll
    for (int e = 0; e < NE; ++e) gc += g_lds[tid * 17 + e] * c3[e];
    out[m0 + tid] = sum + gc + head_b[0];
  }
}

// ---------------------------------------------------------------------------
extern "C" void kernel_launch(void* const* d_in, const int* in_sizes, int n_in,
                              void* d_out, int out_size, void* d_ws, size_t ws_size,
                              hipStream_t stream) {
  const float* x      = (const float*)d_in[0];
  const float* gate_w = (const float*)d_in[1];
  const float* gate_b = (const float*)d_in[2];
  const float* W1     = (const float*)d_in[3];
  const float* b1     = (const float*)d_in[4];
  const float* W2     = (const float*)d_in[5];
  const float* b2     = (const float*)d_in[6];
  const float* W3     = (const float*)d_in[7];
  const float* b3     = (const float*)d_in[8];
  const float* head_w = (const float*)d_in[9];
  const float* head_b = (const float*)d_in[10];
  float* out = (float*)d_out;

  // workspace layout (16B-aligned)
  char* ws = (char*)d_ws;
  _Float16* w1p = (_Float16*)(ws);                 // 4,194,304 B
  _Float16* w2p = (_Float16*)(ws + 4194304);       // 4,194,304 B
  _Float16* gwp = (_Float16*)(ws + 8388608);       // 8,192 B
  float*    w3h = (float*)(ws + 8396800);          // 16,384 B
  float*    c3  = (float*)(ws + 8413184);          // 64 B

  hipLaunchKernelGGL(prep_kernel, dim3(2066), dim3(256), 0, stream,
                     W1, W2, W3, b3, head_w, gate_w, w1p, w2p, w3h, c3, gwp);
  hipLaunchKernelGGL(moe_main, dim3(B_TOK / TK), dim3(1024), 0, stream,
                     x, b1, b2, w1p, w2p, gwp, gate_b, w3h, c3, head_b, out);
}

// Round 5
// 410.852 us; speedup vs baseline: 1.6074x; 1.6074x over previous
//
#include <hip/hip_runtime.h>

// Problem constants
#define B_TOK 32768
#define D_IN  256
#define H1D   512
#define H2D   256
#define NE    16
#define NO    64

typedef _Float16 half8 __attribute__((ext_vector_type(8)));
typedef _Float16 half4 __attribute__((ext_vector_type(4)));
typedef float   float4_t __attribute__((ext_vector_type(4)));

// ---------------------------------------------------------------------------
// Fused prep kernel (grid 2066 x 256):
//  blocks 0..1023    : pack W1 [E][D][H1] fp32 -> fragment-linear fp16
//  blocks 1024..2047 : pack W2 [E][H1][H2] fp32 -> fragment-linear fp16
//  blocks 2048..2064 : w3h[e][h2] = W3[e][h2][:].head_w ; c3[e] = b3[e][:].head_w
//  block  2065       : pack gate_w [D][E] -> 8 B-fragments
// ---------------------------------------------------------------------------
__global__ void prep_kernel(const float* __restrict__ W1, const float* __restrict__ W2,
                            const float* __restrict__ W3, const float* __restrict__ b3,
                            const float* __restrict__ hw, const float* __restrict__ gw,
                            _Float16* __restrict__ w1p, _Float16* __restrict__ w2p,
                            float* __restrict__ w3h, float* __restrict__ c3,
                            _Float16* __restrict__ gwp) {
  int blk = blockIdx.x;
  int tid = threadIdx.x;
  if (blk < 1024) {
    int t = blk * 256 + tid;                     // 262144 threads
    int lane = t & 63;
    int kt   = (t >> 6) & 7;
    int ntg  = (t >> 9) & 31;
    int e    = t >> 14;
    int n  = ntg * 16 + (lane & 15);
    int kb = kt * 32 + (lane >> 4) * 8;
    half8 v;
    #pragma unroll
    for (int j = 0; j < 8; ++j)
      v[j] = (_Float16)W1[((size_t)(e * D_IN + kb + j)) * H1D + n];
    *(half8*)(w1p + (size_t)t * 8) = v;
  } else if (blk < 2048) {
    int t = (blk - 1024) * 256 + tid;            // 262144 threads
    int lane = t & 63;
    int ktg  = (t >> 6) & 15;
    int ntg  = (t >> 10) & 15;
    int e    = t >> 14;
    int n  = ntg * 16 + (lane & 15);
    int kb = ktg * 32 + (lane >> 4) * 8;
    half8 v;
    #pragma unroll
    for (int j = 0; j < 8; ++j)
      v[j] = (_Float16)W2[((size_t)(e * H1D + kb + j)) * H2D + n];
    *(half8*)(w2p + (size_t)t * 8) = v;
  } else if (blk < 2065) {
    int t = (blk - 2048) * 256 + tid;
    if (t < NE * H2D) {
      int e = t >> 8, h = t & 255;
      float s = 0.f;
      #pragma unroll
      for (int o = 0; o < NO; ++o) s = fmaf(W3[((size_t)(e * H2D + h)) * NO + o], hw[o], s);
      w3h[t] = s;
    } else if (t < NE * H2D + NE) {
      int e = t - NE * H2D;
      float s = 0.f;
      #pragma unroll
      for (int o = 0; o < NO; ++o) s = fmaf(b3[e * NO + o], hw[o], s);
      c3[e] = s;
    }
  } else {
    for (int t = tid; t < 512; t += 256) {
      int lane = t & 63;
      int kt   = t >> 6;
      int e  = lane & 15;
      int kb = kt * 32 + (lane >> 4) * 8;
      half8 v;
      #pragma unroll
      for (int j = 0; j < 8; ++j)
        v[j] = (_Float16)gw[(kb + j) * NE + e];
      *(half8*)(gwp + (size_t)t * 8) = v;
    }
  }
}

// ---------------------------------------------------------------------------
// Fused main kernel. 512 blocks x 256 threads (4 waves), 64 tokens/block,
// 2 blocks/CU (R2-proven config). x tile in registers for the whole kernel.
// Per expert: L1 (transposed: A=W1^T frags global, B=x regs) -> h1 [64][512]
// in LDS (b64 stores) -> barrier -> L2 (A=h1 LDS, B=W2 frags global) ->
// register epilogue with gate folded into per-lane yacc -> barrier (WAR).
// Exactly 2 barriers/expert; single shuffle-reduce at the end.
// ---------------------------------------------------------------------------
#define H1STR 520   // halves: 512 + 8 pad

__global__ __launch_bounds__(256, 2) void moe_main(
    const float* __restrict__ x,
    const float* __restrict__ b1,
    const float* __restrict__ b2,
    const _Float16* __restrict__ w1p,
    const _Float16* __restrict__ w2p,
    const _Float16* __restrict__ gwp,
    const float* __restrict__ gb,
    const float* __restrict__ w3h,
    const float* __restrict__ c3,
    const float* __restrict__ head_b,
    float* __restrict__ out) {
  __shared__ _Float16 h1_lds[64 * H1STR];          // 66.5 KB
  __shared__ float g_lds[64 * 17];                 // [token][e] padded
  __shared__ float fin[4 * 64];

  const int tid  = threadIdx.x;
  const int w    = tid >> 6;
  const int lane = tid & 63;
  const int q    = lane >> 4;
  const int l16  = lane & 15;
  const int m0   = blockIdx.x * 64;

  // ---- one-time: load x tile into register fragments xf[token-tile][kt] ----
  half8 xf[4][8];
  #pragma unroll
  for (int nt = 0; nt < 4; ++nt) {
    const float* xr = x + (size_t)(m0 + nt * 16 + l16) * D_IN + q * 8;
    #pragma unroll
    for (int kt = 0; kt < 8; ++kt) {
      float4_t v0 = *(const float4_t*)(xr + kt * 32);
      float4_t v1 = *(const float4_t*)(xr + kt * 32 + 4);
      half8 h;
      h[0] = (_Float16)v0[0]; h[1] = (_Float16)v0[1];
      h[2] = (_Float16)v0[2]; h[3] = (_Float16)v0[3];
      h[4] = (_Float16)v1[0]; h[5] = (_Float16)v1[1];
      h[6] = (_Float16)v1[2]; h[7] = (_Float16)v1[3];
      xf[nt][kt] = h;
    }
  }

  // ---- one-time: gates via MFMA + shuffle softmax; wave w does tile mt==w --
  {
    float gbv = gb[l16];
    #pragma unroll
    for (int mt = 0; mt < 4; ++mt) {
      if (mt == w) {   // wave-uniform branch; mt stays compile-time constant
        float4_t lg = (float4_t){0.f, 0.f, 0.f, 0.f};
        #pragma unroll
        for (int kt = 0; kt < 8; ++kt) {
          half8 bfr = *(const half8*)(gwp + (size_t)kt * 512 + lane * 8);
          lg = __builtin_amdgcn_mfma_f32_16x16x32_f16(xf[mt][kt], bfr, lg, 0, 0, 0);
        }
        #pragma unroll
        for (int r = 0; r < 4; ++r) {
          float v = lg[r] + gbv;                   // logit[token][e=l16]
          float m = v;
          m = fmaxf(m, __shfl_xor(m, 1));
          m = fmaxf(m, __shfl_xor(m, 2));
          m = fmaxf(m, __shfl_xor(m, 4));
          m = fmaxf(m, __shfl_xor(m, 8));
          float p = __expf(v - m);
          float s = p;
          s += __shfl_xor(s, 1);
          s += __shfl_xor(s, 2);
          s += __shfl_xor(s, 4);
          s += __shfl_xor(s, 8);
          g_lds[(mt * 16 + q * 4 + r) * 17 + l16] = p / s;
        }
      }
    }
  }

  float yacc[4][4];    // gated accumulator: [mt][r] for token mt*16+q*4+r
  #pragma unroll
  for (int mt = 0; mt < 4; ++mt)
    #pragma unroll
    for (int r = 0; r < 4; ++r) yacc[mt][r] = 0.f;

  for (int e = 0; e < NE; ++e) {
    // ================= L1: h1^T tiles, write h1_lds[token][h1col] ===========
    #pragma unroll
    for (int ch = 0; ch < 2; ++ch) {
      float4_t a1[4][4];
      #pragma unroll
      for (int mt = 0; mt < 4; ++mt)
        #pragma unroll
        for (int nt = 0; nt < 4; ++nt)
          a1[mt][nt] = (float4_t){0.f, 0.f, 0.f, 0.f};

      const _Float16* wbase =
          w1p + ((size_t)((e * 32 + ch * 16 + w * 4) * 8)) * 512 + lane * 8;
      #pragma unroll
      for (int kt = 0; kt < 8; ++kt) {
        half8 wc[4];
        #pragma unroll
        for (int mt = 0; mt < 4; ++mt)
          wc[mt] = *(const half8*)(wbase + (size_t)(mt * 8 + kt) * 512);
        #pragma unroll
        for (int mt = 0; mt < 4; ++mt)
          #pragma unroll
          for (int nt = 0; nt < 4; ++nt)
            a1[mt][nt] = __builtin_amdgcn_mfma_f32_16x16x32_f16(
                wc[mt], xf[nt][kt], a1[mt][nt], 0, 0, 0);
      }

      // bias + relu + b64 stores (lane: 4 consecutive h1cols of one token)
      #pragma unroll
      for (int mt = 0; mt < 4; ++mt) {
        int colbase = ch * 256 + (w * 4 + mt) * 16 + q * 4;
        float4_t bb = *(const float4_t*)(b1 + e * H1D + colbase);
        #pragma unroll
        for (int nt = 0; nt < 4; ++nt) {
          half4 hv;
          #pragma unroll
          for (int r = 0; r < 4; ++r)
            hv[r] = (_Float16)fmaxf(a1[mt][nt][r] + bb[r], 0.f);
          *(half4*)(h1_lds + (nt * 16 + l16) * H1STR + colbase) = hv;
        }
      }
    }

    // hoist this expert's epilogue constants (independent of h1)
    float b2v[4], w3v[4];
    #pragma unroll
    for (int nt = 0; nt < 4; ++nt) {
      int n = w * 64 + nt * 16 + l16;
      b2v[nt] = b2[e * H2D + n];
      w3v[nt] = w3h[e * H2D + n];
    }

    __syncthreads();   // B1: h1 complete & visible (also g_lds at e=0)

    // ================= L2: h2 = h1 @ W2, wave owns h2cols [w*64,w*64+64) ====
    float4_t h2[4][4];
    #pragma unroll
    for (int mt = 0; mt < 4; ++mt)
      #pragma unroll
      for (int nt = 0; nt < 4; ++nt)
        h2[mt][nt] = (float4_t){0.f, 0.f, 0.f, 0.f};

    const _Float16* w2base =
        w2p + ((size_t)((e * 16 + w * 4) * 16)) * 512 + lane * 8;
    #pragma unroll
    for (int kt = 0; kt < 16; ++kt) {
      half8 w2c[4];
      #pragma unroll
      for (int nt = 0; nt < 4; ++nt)
        w2c[nt] = *(const half8*)(w2base + (size_t)(nt * 16 + kt) * 512);
      half8 hac[4];
      #pragma unroll
      for (int mt = 0; mt < 4; ++mt)
        hac[mt] = *(const half8*)(h1_lds + (mt * 16 + l16) * H1STR + kt * 32 + q * 8);
      #pragma unroll
      for (int mt = 0; mt < 4; ++mt)
        #pragma unroll
        for (int nt = 0; nt < 4; ++nt)
          h2[mt][nt] = __builtin_amdgcn_mfma_f32_16x16x32_f16(
              hac[mt], w2c[nt], h2[mt][nt], 0, 0, 0);
    }

    // ---- register epilogue: relu(h2+b2).w3h, gate folded, accumulate ------
    #pragma unroll
    for (int mt = 0; mt < 4; ++mt) {
      #pragma unroll
      for (int r = 0; r < 4; ++r) {
        float s = 0.f;
        #pragma unroll
        for (int nt = 0; nt < 4; ++nt)
          s += fmaxf(h2[mt][nt][r] + b2v[nt], 0.f) * w3v[nt];
        yacc[mt][r] += g_lds[(mt * 16 + q * 4 + r) * 17 + e] * s;
      }
    }
    __syncthreads();   // B2 (WAR): all h1 reads done before next L1 writes
  }

  // ---- single final reduction: sum yacc over the 16 l16-lanes (cols) ------
  #pragma unroll
  for (int mt = 0; mt < 4; ++mt) {
    #pragma unroll
    for (int r = 0; r < 4; ++r) {
      float v = yacc[mt][r];
      v += __shfl_xor(v, 1);
      v += __shfl_xor(v, 2);
      v += __shfl_xor(v, 4);
      v += __shfl_xor(v, 8);
      yacc[mt][r] = v;                 // all l16 lanes now hold the sum
    }
  }
  if (l16 == 0) {
    #pragma unroll
    for (int mt = 0; mt < 4; ++mt)
      #pragma unroll
      for (int r = 0; r < 4; ++r)
        fin[w * 64 + mt * 16 + q * 4 + r] = yacc[mt][r];
  }
  __syncthreads();
  if (tid < 64) {
    float sum = fin[tid] + fin[64 + tid] + fin[128 + tid] + fin[192 + tid];
    float gc = 0.f;
    #pragma unroll
    for (int e = 0; e < NE; ++e) gc += g_lds[tid * 17 + e] * c3[e];
    out[m0 + tid] = sum + gc + head_b[0];
  }
}

// ---------------------------------------------------------------------------
extern "C" void kernel_launch(void* const* d_in, const int* in_sizes, int n_in,
                              void* d_out, int out_size, void* d_ws, size_t ws_size,
                              hipStream_t stream) {
  const float* x      = (const float*)d_in[0];
  const float* gate_w = (const float*)d_in[1];
  const float* gate_b = (const float*)d_in[2];
  const float* W1     = (const float*)d_in[3];
  const float* b1     = (const float*)d_in[4];
  const float* W2     = (const float*)d_in[5];
  const float* b2     = (const float*)d_in[6];
  const float* W3     = (const float*)d_in[7];
  const float* b3     = (const float*)d_in[8];
  const float* head_w = (const float*)d_in[9];
  const float* head_b = (const float*)d_in[10];
  float* out = (float*)d_out;

  // workspace layout (16B-aligned)
  char* ws = (char*)d_ws;
  _Float16* w1p = (_Float16*)(ws);                 // 4,194,304 B
  _Float16* w2p = (_Float16*)(ws + 4194304);       // 4,194,304 B
  _Float16* gwp = (_Float16*)(ws + 8388608);       // 8,192 B
  float*    w3h = (float*)(ws + 8396800);          // 16,384 B
  float*    c3  = (float*)(ws + 8413184);          // 64 B

  hipLaunchKernelGGL(prep_kernel, dim3(2066), dim3(256), 0, stream,
                     W1, W2, W3, b3, head_w, gate_w, w1p, w2p, w3h, c3, gwp);
  hipLaunchKernelGGL(moe_main, dim3(B_TOK / 64), dim3(256), 0, stream,
                     x, b1, b2, w1p, w2p, gwp, gate_b, w3h, c3, head_b, out);
}

// Round 6
// 363.884 us; speedup vs baseline: 1.8149x; 1.1291x over previous
//
#include <hip/hip_runtime.h>

// Problem constants
#define B_TOK 32768
#define D_IN  256
#define H1D   512
#define H2D   256
#define NE    16
#define NO    64

typedef _Float16 half8 __attribute__((ext_vector_type(8)));
typedef _Float16 half4 __attribute__((ext_vector_type(4)));
typedef float   float4_t __attribute__((ext_vector_type(4)));

// ---------------------------------------------------------------------------
// Fused prep kernel (grid 2066 x 256):
//  blocks 0..1023    : pack W1 [E][D][H1] fp32 -> fragment-linear fp16
//  blocks 1024..2047 : pack W2 [E][H1][H2] fp32 -> fragment-linear fp16
//  blocks 2048..2064 : w3h[e][h2] = W3[e][h2][:].head_w ; c3[e] = b3[e][:].head_w
//  block  2065       : pack gate_w [D][E] -> 8 B-fragments
// ---------------------------------------------------------------------------
__global__ void prep_kernel(const float* __restrict__ W1, const float* __restrict__ W2,
                            const float* __restrict__ W3, const float* __restrict__ b3,
                            const float* __restrict__ hw, const float* __restrict__ gw,
                            _Float16* __restrict__ w1p, _Float16* __restrict__ w2p,
                            float* __restrict__ w3h, float* __restrict__ c3,
                            _Float16* __restrict__ gwp) {
  int blk = blockIdx.x;
  int tid = threadIdx.x;
  if (blk < 1024) {
    int t = blk * 256 + tid;                     // 262144 threads
    int lane = t & 63;
    int kt   = (t >> 6) & 7;
    int ntg  = (t >> 9) & 31;
    int e    = t >> 14;
    int n  = ntg * 16 + (lane & 15);
    int kb = kt * 32 + (lane >> 4) * 8;
    half8 v;
    #pragma unroll
    for (int j = 0; j < 8; ++j)
      v[j] = (_Float16)W1[((size_t)(e * D_IN + kb + j)) * H1D + n];
    *(half8*)(w1p + (size_t)t * 8) = v;
  } else if (blk < 2048) {
    int t = (blk - 1024) * 256 + tid;            // 262144 threads
    int lane = t & 63;
    int ktg  = (t >> 6) & 15;
    int ntg  = (t >> 10) & 15;
    int e    = t >> 14;
    int n  = ntg * 16 + (lane & 15);
    int kb = ktg * 32 + (lane >> 4) * 8;
    half8 v;
    #pragma unroll
    for (int j = 0; j < 8; ++j)
      v[j] = (_Float16)W2[((size_t)(e * H1D + kb + j)) * H2D + n];
    *(half8*)(w2p + (size_t)t * 8) = v;
  } else if (blk < 2065) {
    int t = (blk - 2048) * 256 + tid;
    if (t < NE * H2D) {
      int e = t >> 8, h = t & 255;
      float s = 0.f;
      #pragma unroll
      for (int o = 0; o < NO; ++o) s = fmaf(W3[((size_t)(e * H2D + h)) * NO + o], hw[o], s);
      w3h[t] = s;
    } else if (t < NE * H2D + NE) {
      int e = t - NE * H2D;
      float s = 0.f;
      #pragma unroll
      for (int o = 0; o < NO; ++o) s = fmaf(b3[e * NO + o], hw[o], s);
      c3[e] = s;
    }
  } else {
    for (int t = tid; t < 512; t += 256) {
      int lane = t & 63;
      int kt   = t >> 6;
      int e  = lane & 15;
      int kb = kt * 32 + (lane >> 4) * 8;
      half8 v;
      #pragma unroll
      for (int j = 0; j < 8; ++j)
        v[j] = (_Float16)gw[(kb + j) * NE + e];
      *(half8*)(gwp + (size_t)t * 8) = v;
    }
  }
}

// ---------------------------------------------------------------------------
// Fused main kernel. 512 blocks x 256 threads (4 waves), 64 tokens/block,
// 2 blocks/CU. x staged ONCE into LDS as fragment-linear fp16 (zero VGPR
// residency, conflict-free ds_read_b128). h1 is a single 256-col chunk
// buffer; L1/L2 interleave per chunk, h2 accumulates across chunks:
//   for ch: L1ch (w1 global + x LDS) -> h1ch -> barrier ->
//           L2ch-partial (h1ch LDS + w2 global) -> barrier (WAR)
// Deferred-gate epilogue in registers; single shuffle-reduce at the end.
// Low register pressure (~100 arch + 128 acc) -> deep weight prefetch.
// ---------------------------------------------------------------------------
#define H1CSTR 266   // halves: 256 + 10 pad (row stride 133 dw, odd -> <=2-way)

__global__ __launch_bounds__(256, 2) void moe_main(
    const float* __restrict__ x,
    const float* __restrict__ b1,
    const float* __restrict__ b2,
    const _Float16* __restrict__ w1p,
    const _Float16* __restrict__ w2p,
    const _Float16* __restrict__ gwp,
    const float* __restrict__ gb,
    const float* __restrict__ w3h,
    const float* __restrict__ c3,
    const float* __restrict__ head_b,
    float* __restrict__ out) {
  __shared__ _Float16 x_lds[32 * 512];             // 32 KB, fragment-linear
  __shared__ _Float16 h1c[64 * H1CSTR];            // 34,048 B (one 256-col chunk)
  __shared__ float g_lds[64 * 17];                 // 4,352 B [token][e]
  __shared__ float fin[4 * 64];                    // 1,024 B

  const int tid  = threadIdx.x;
  const int w    = tid >> 6;
  const int lane = tid & 63;
  const int q    = lane >> 4;
  const int l16  = lane & 15;
  const int m0   = blockIdx.x * 64;

  // ---- stage x tile into LDS as MFMA fragments: frag (nt,kt) at
  //      x_lds[(nt*8+kt)*512 + lane*8], lane holds x[nt*16+l16][kt*32+q*8..+8]
  #pragma unroll
  for (int f = 0; f < 8; ++f) {
    const float* xr = x + (size_t)(m0 + w * 16 + l16) * D_IN + f * 32 + q * 8;
    float4_t v0 = *(const float4_t*)(xr);
    float4_t v1 = *(const float4_t*)(xr + 4);
    half8 h;
    h[0] = (_Float16)v0[0]; h[1] = (_Float16)v0[1];
    h[2] = (_Float16)v0[2]; h[3] = (_Float16)v0[3];
    h[4] = (_Float16)v1[0]; h[5] = (_Float16)v1[1];
    h[6] = (_Float16)v1[2]; h[7] = (_Float16)v1[3];
    *(half8*)(x_lds + (size_t)(w * 8 + f) * 512 + lane * 8) = h;
  }
  __syncthreads();   // x_lds ready

  // ---- gates via MFMA + shuffle softmax; wave w handles token tile w -------
  {
    float gbv = gb[l16];
    float4_t lg = (float4_t){0.f, 0.f, 0.f, 0.f};
    #pragma unroll
    for (int kt = 0; kt < 8; ++kt) {
      half8 xa = *(const half8*)(x_lds + (size_t)(w * 8 + kt) * 512 + lane * 8);
      half8 bfr = *(const half8*)(gwp + (size_t)kt * 512 + lane * 8);
      lg = __builtin_amdgcn_mfma_f32_16x16x32_f16(xa, bfr, lg, 0, 0, 0);
    }
    #pragma unroll
    for (int r = 0; r < 4; ++r) {
      float v = lg[r] + gbv;                       // logit[token][e=l16]
      float m = v;
      m = fmaxf(m, __shfl_xor(m, 1));
      m = fmaxf(m, __shfl_xor(m, 2));
      m = fmaxf(m, __shfl_xor(m, 4));
      m = fmaxf(m, __shfl_xor(m, 8));
      float p = __expf(v - m);
      float s = p;
      s += __shfl_xor(s, 1);
      s += __shfl_xor(s, 2);
      s += __shfl_xor(s, 4);
      s += __shfl_xor(s, 8);
      g_lds[(w * 16 + q * 4 + r) * 17 + l16] = p / s;
    }
  }
  // no barrier needed: g_lds becomes visible via the barrier inside the loop
  // before any epilogue read (first epilogue is after two __syncthreads).

  float yacc[4][4];    // gated accumulator: [mt][r] for token mt*16+q*4+r
  #pragma unroll
  for (int mt = 0; mt < 4; ++mt)
    #pragma unroll
    for (int r = 0; r < 4; ++r) yacc[mt][r] = 0.f;

  for (int e = 0; e < NE; ++e) {
    float4_t h2[4][4];   // accumulates across both chunks
    #pragma unroll
    for (int mt = 0; mt < 4; ++mt)
      #pragma unroll
      for (int nt = 0; nt < 4; ++nt)
        h2[mt][nt] = (float4_t){0.f, 0.f, 0.f, 0.f};

    #pragma unroll
    for (int ch = 0; ch < 2; ++ch) {
      // ===== L1 chunk: h1[ch*256 .. +256) (transposed, A=W1^T, B=x) ========
      float4_t a1[4][4];
      #pragma unroll
      for (int mt = 0; mt < 4; ++mt)
        #pragma unroll
        for (int nt = 0; nt < 4; ++nt)
          a1[mt][nt] = (float4_t){0.f, 0.f, 0.f, 0.f};

      const _Float16* w1e =
          w1p + ((size_t)((e * 32 + ch * 16 + w * 4) * 8)) * 512 + lane * 8;
      #pragma unroll
      for (int kt = 0; kt < 8; ++kt) {
        half8 wc[4];
        #pragma unroll
        for (int mt = 0; mt < 4; ++mt)
          wc[mt] = *(const half8*)(w1e + (size_t)(mt * 8 + kt) * 512);
        half8 xb[4];
        #pragma unroll
        for (int nt = 0; nt < 4; ++nt)
          xb[nt] = *(const half8*)(x_lds + (size_t)(nt * 8 + kt) * 512 + lane * 8);
        #pragma unroll
        for (int mt = 0; mt < 4; ++mt)
          #pragma unroll
          for (int nt = 0; nt < 4; ++nt)
            a1[mt][nt] = __builtin_amdgcn_mfma_f32_16x16x32_f16(
                wc[mt], xb[nt], a1[mt][nt], 0, 0, 0);
      }

      // bias + relu + b64 stores into the chunk buffer (local cols 0..255)
      #pragma unroll
      for (int mt = 0; mt < 4; ++mt) {
        int colbase = (w * 4 + mt) * 16 + q * 4;   // local col
        float4_t bb = *(const float4_t*)(b1 + e * H1D + ch * 256 + colbase);
        #pragma unroll
        for (int nt = 0; nt < 4; ++nt) {
          half4 hv;
          #pragma unroll
          for (int r = 0; r < 4; ++r)
            hv[r] = (_Float16)fmaxf(a1[mt][nt][r] + bb[r], 0.f);
          *(half4*)(h1c + (nt * 16 + l16) * H1CSTR + colbase) = hv;
        }
      }

      __syncthreads();   // h1 chunk ready

      // ===== L2 partial: h2 += h1c @ W2[ch*256.., wave's 64 cols] ==========
      const _Float16* w2e =
          w2p + ((size_t)((e * 16 + w * 4) * 16 + ch * 8)) * 512 + lane * 8;
      #pragma unroll
      for (int kt = 0; kt < 8; ++kt) {
        half8 w2c[4];
        #pragma unroll
        for (int nt = 0; nt < 4; ++nt)
          w2c[nt] = *(const half8*)(w2e + (size_t)(nt * 16 + kt) * 512);
        half8 hac[4];
        #pragma unroll
        for (int mt = 0; mt < 4; ++mt)
          hac[mt] = *(const half8*)(h1c + (mt * 16 + l16) * H1CSTR + kt * 32 + q * 8);
        #pragma unroll
        for (int mt = 0; mt < 4; ++mt)
          #pragma unroll
          for (int nt = 0; nt < 4; ++nt)
            h2[mt][nt] = __builtin_amdgcn_mfma_f32_16x16x32_f16(
                hac[mt], w2c[nt], h2[mt][nt], 0, 0, 0);
      }

      __syncthreads();   // WAR: h1c reads done before next chunk/expert L1
    }

    // ---- register epilogue: relu(h2+b2).w3h, gate folded, accumulate ------
    float b2v[4], w3v[4];
    #pragma unroll
    for (int nt = 0; nt < 4; ++nt) {
      int n = w * 64 + nt * 16 + l16;
      b2v[nt] = b2[e * H2D + n];
      w3v[nt] = w3h[e * H2D + n];
    }
    #pragma unroll
    for (int mt = 0; mt < 4; ++mt) {
      #pragma unroll
      for (int r = 0; r < 4; ++r) {
        float s = 0.f;
        #pragma unroll
        for (int nt = 0; nt < 4; ++nt)
          s += fmaxf(h2[mt][nt][r] + b2v[nt], 0.f) * w3v[nt];
        yacc[mt][r] += g_lds[(mt * 16 + q * 4 + r) * 17 + e] * s;
      }
    }
  }

  // ---- single final reduction: sum yacc over the 16 l16-lanes (cols) ------
  #pragma unroll
  for (int mt = 0; mt < 4; ++mt) {
    #pragma unroll
    for (int r = 0; r < 4; ++r) {
      float v = yacc[mt][r];
      v += __shfl_xor(v, 1);
      v += __shfl_xor(v, 2);
      v += __shfl_xor(v, 4);
      v += __shfl_xor(v, 8);
      yacc[mt][r] = v;
    }
  }
  if (l16 == 0) {
    #pragma unroll
    for (int mt = 0; mt < 4; ++mt)
      #pragma unroll
      for (int r = 0; r < 4; ++r)
        fin[w * 64 + mt * 16 + q * 4 + r] = yacc[mt][r];
  }
  __syncthreads();
  if (tid < 64) {
    float sum = fin[tid] + fin[64 + tid] + fin[128 + tid] + fin[192 + tid];
    float gc = 0.f;
    #pragma unroll
    for (int e = 0; e < NE; ++e) gc += g_lds[tid * 17 + e] * c3[e];
    out[m0 + tid] = sum + gc + head_b[0];
  }
}

// ---------------------------------------------------------------------------
extern "C" void kernel_launch(void* const* d_in, const int* in_sizes, int n_in,
                              void* d_out, int out_size, void* d_ws, size_t ws_size,
                              hipStream_t stream) {
  const float* x      = (const float*)d_in[0];
  const float* gate_w = (const float*)d_in[1];
  const float* gate_b = (const float*)d_in[2];
  const float* W1     = (const float*)d_in[3];
  const float* b1     = (const float*)d_in[4];
  const float* W2     = (const float*)d_in[5];
  const float* b2     = (const float*)d_in[6];
  const float* W3     = (const float*)d_in[7];
  const float* b3     = (const float*)d_in[8];
  const float* head_w = (const float*)d_in[9];
  const float* head_b = (const float*)d_in[10];
  float* out = (float*)d_out;

  // workspace layout (16B-aligned)
  char* ws = (char*)d_ws;
  _Float16* w1p = (_Float16*)(ws);                 // 4,194,304 B
  _Float16* w2p = (_Float16*)(ws + 4194304);       // 4,194,304 B
  _Float16* gwp = (_Float16*)(ws + 8388608);       // 8,192 B
  float*    w3h = (float*)(ws + 8396800);          // 16,384 B
  float*    c3  = (float*)(ws + 8413184);          // 64 B

  hipLaunchKernelGGL(prep_kernel, dim3(2066), dim3(256), 0, stream,
                     W1, W2, W3, b3, head_w, gate_w, w1p, w2p, w3h, c3, gwp);
  hipLaunchKernelGGL(moe_main, dim3(B_TOK / 64), dim3(256), 0, stream,
                     x, b1, b2, w1p, w2p, gwp, gate_b, w3h, c3, head_b, out);
}